// Round 12
// baseline (99.828 us; speedup 1.0000x reference)
//
#include <hip/hip_runtime.h>
#include <math.h>

#define R_ 25
#define N_ 256
#define C_ 64
#define E_ 128
#define H_ 8
#define NC_ 27
#define SQS 28   // padded row stride for sqrt-softmax tables

typedef _Float16 f16x8 __attribute__((ext_vector_type(8)));
typedef float f32x16 __attribute__((ext_vector_type(16)));

union HU { ushort s; _Float16 h; };
__device__ __forceinline__ ushort ftoh(float f) { HU u; u.h = (_Float16)f; return u.s; }
__device__ __forceinline__ float htof(ushort s) { HU u; u.s = s; return (float)u.h; }

__device__ __forceinline__ float waveReduceSum(float v) {
  #pragma unroll
  for (int off = 32; off > 0; off >>= 1) v += __shfl_xor(v, off);
  return v;
}

// ==================== 1. PREP ==============================================
// grid: [0,1600) emb_ln | [1600,1689) mean4 | [1689,2045) sqsm (4 lanes/row)
//       2045 groups | [2046,2078) os-proj | [2078,2094) Gt MFMA
__global__ __launch_bounds__(256) void k_prep(
    const float* __restrict__ emb, const float* __restrict__ ln_w,
    const float* __restrict__ ln_b, ushort* __restrict__ emb16,
    const float* __restrict__ bus_t, const float* __restrict__ bus_i,
    float* __restrict__ bst, float* __restrict__ bsi,
    const float* __restrict__ cus_t, const float* __restrict__ cus_i,
    float* __restrict__ Ssq, float* __restrict__ Tsq,
    const int* __restrict__ idx_t, const int* __restrict__ idx_i,
    int* __restrict__ cnt, int* __restrict__ lst,
    const int* __restrict__ biz, const float* __restrict__ Wos,
    const float* __restrict__ bos, float* __restrict__ projb,
    const float* __restrict__ WQt_, const float* __restrict__ WKt_,
    const float* __restrict__ WQi_, const float* __restrict__ WKi_,
    ushort* __restrict__ Gt) {
  __shared__ uint sbuf[16384];   // 64KB, reused per branch
  int bid = blockIdx.x, t = threadIdx.x;
  if (bid < 1600) {
    // ---- emb layernorm -> f16, 4 rows/block ----
    int row = bid * 4 + (t >> 6);
    int lane = t & 63;
    const float2* x = (const float2*)(emb + (size_t)row * E_);
    float2 v = x[lane];
    float s = waveReduceSum(v.x + v.y);
    float m = s * (1.0f / 128.0f);
    float d0 = v.x - m, d1 = v.y - m;
    float ss = waveReduceSum(d0 * d0 + d1 * d1);
    float inv = 1.0f / sqrtf(ss * (1.0f / 128.0f) + 1e-16f);
    float2 wv = ((const float2*)ln_w)[lane];
    float2 bv = ((const float2*)ln_b)[lane];
    uint u = (uint)ftoh(d0 * inv * wv.x + bv.x) | ((uint)ftoh(d1 * inv * wv.y + bv.y) << 16);
    ((uint*)emb16)[(size_t)row * 64 + lane] = u;
  } else if (bid < 1689) {
    // ---- mean over trailing 4 ----
    int i = (bid - 1600) * 256 + t;
    if (i < R_ * N_) {
      size_t row = (size_t)(i >> 8) * (C_ * N_) + (i & 255);
      float4 v = *(const float4*)&bus_t[row * 4];
      bst[i] = (v.x + v.y + v.z + v.w) * 0.25f;
    }
    int j = i - R_ * N_;
    if (j >= 0 && j < C_ * N_) {
      float4 v = *(const float4*)&bus_i[(size_t)j * 4];
      bsi[j] = (v.x + v.y + v.z + v.w) * 0.25f;
    }
  } else if (bid < 2045) {
    // ---- sqrt(softmax(mean4 over 27)), 4 lanes per row ----
    int gidx = (bid - 1689) * 256 + t;
    int rowi = gidx >> 2, sub = gidx & 3;
    const float* src; float* dst; size_t base; int oi;
    if (rowi < R_ * N_) {
      src = cus_t; dst = Ssq; oi = rowi;
      base = ((size_t)(rowi >> 8) * (C_ * N_) + (rowi & 255)) * (NC_ * 4);
    } else {
      int j = rowi - R_ * N_;
      if (j >= C_ * N_) return;
      src = cus_i; dst = Tsq; oi = j;
      base = ((size_t)(j >> 8) * N_ + (j & 255)) * (NC_ * 4);
    }
    int j0 = sub * 7;
    int nj = (sub == 3) ? 6 : 7;
    float v[7];
    float mx = -1e30f;
    #pragma unroll
    for (int k = 0; k < 7; ++k) {
      if (k < nj) {
        float4 q = *(const float4*)&src[base + (j0 + k) * 4];
        v[k] = (q.x + q.y + q.z + q.w) * 0.25f;
        mx = fmaxf(mx, v[k]);
      }
    }
    mx = fmaxf(mx, __shfl_xor(mx, 1));
    mx = fmaxf(mx, __shfl_xor(mx, 2));
    float se = 0.0f;
    #pragma unroll
    for (int k = 0; k < 7; ++k) if (k < nj) se += expf(v[k] - mx);
    se += __shfl_xor(se, 1);
    se += __shfl_xor(se, 2);
    float lse = mx + logf(se);
    #pragma unroll
    for (int k = 0; k < 7; ++k)
      if (k < nj) dst[(size_t)oi * SQS + j0 + k] = expf(0.5f * (v[k] - lse));
    if (sub == 3) dst[(size_t)oi * SQS + NC_] = 0.0f;
  } else if (bid == 2045) {
    // ---- group lists ----
    if (t < 2 * R_) cnt[t] = 0;
    __syncthreads();
    if (t < R_) {
      int rr = idx_t[t * C_];
      int pos = atomicAdd(&cnt[rr], 1);
      lst[rr * 64 + pos] = t;
    }
    if (t < C_) {
      int rr = idx_i[t];
      int pos = atomicAdd(&cnt[R_ + rr], 1);
      lst[(R_ + rr) * 64 + pos] = t;
    }
  } else if (bid < 2078) {
    // ---- OS projection: proj[c][f] = emb[row_c] . Wos[f] + bos[f], 2 c/block ----
    float* er2 = (float*)sbuf;    // [2][128]
    int pb = bid - 2046;
    int ci = t >> 7, f = t & 127;
    int c = pb * 2 + ci;
    int row = idx_i[c] * N_ + biz[c];
    er2[ci * E_ + f] = emb[(size_t)row * E_ + f];
    __syncthreads();
    float acc = bos[f];
    const float* wr = &Wos[(size_t)f * E_];
    const float* er = &er2[ci * E_];
    for (int e = 0; e < E_; e += 4) {
      float4 w4 = *(const float4*)&wr[e];
      acc += er[e] * w4.x + er[e + 1] * w4.y + er[e + 2] * w4.z + er[e + 3] * w4.w;
    }
    projb[c * E_ + f] = acc;
  } else {
    // ---- Gt[set,h][e'][e] = sum_f WK[h,f,e']*WQ[h,f,e]/sqrt(E), MFMA ----
    int gb = bid - 2078;
    int h = gb & 7, set = gb >> 3;
    const float* WQ = (set ? WQi_ : WQt_) + ((size_t)h << 14);
    const float* WK = (set ? WKi_ : WKt_) + ((size_t)h << 14);
    uint* QT = sbuf;          // [e][f2 swz]
    uint* KT = sbuf + 8192;   // [e'][f2 swz]
    for (int j = t; j < 8192; j += 256) {
      int e = j & 127, f2 = j >> 7;
      int wi = (f2 << 8) + e;
      float q0 = WQ[wi], q1 = WQ[wi + 128];
      float k0 = WK[wi], k1 = WK[wi + 128];
      int idx = (e << 6) + (f2 ^ ((e & 15) << 2));
      QT[idx] = (uint)ftoh(q0) | ((uint)ftoh(q1) << 16);
      KT[idx] = (uint)ftoh(k0) | ((uint)ftoh(k1) << 16);
    }
    __syncthreads();
    int w = t >> 6, l = t & 63, lo = l & 31, hi = l >> 5;
    int m0 = w << 5;
    f32x16 acc[4];
    #pragma unroll
    for (int i = 0; i < 4; ++i)
      #pragma unroll
      for (int j = 0; j < 16; ++j) acc[i][j] = 0.0f;
    int mrow = m0 + lo;
    #pragma unroll
    for (int ks = 0; ks < 8; ++ks) {
      int f2b = (ks << 3) + (hi << 2);
      f16x8 a = *(const f16x8*)&KT[(mrow << 6) + (f2b ^ ((mrow & 15) << 2))];
      #pragma unroll
      for (int tl = 0; tl < 4; ++tl) {
        int ncol = (tl << 5) + lo;
        f16x8 b = *(const f16x8*)&QT[(ncol << 6) + (f2b ^ ((ncol & 15) << 2))];
        acc[tl] = __builtin_amdgcn_mfma_f32_32x32x16_f16(a, b, acc[tl], 0, 0, 0);
      }
    }
    const float scale = 0.08838834764831845f;   // 1/sqrt(128)
    ushort* Go = Gt + (((size_t)(set * H_ + h)) << 14);
    #pragma unroll
    for (int tl = 0; tl < 4; ++tl)
      #pragma unroll
      for (int rg = 0; rg < 16; ++rg) {
        int row = m0 + (rg & 3) + ((rg >> 2) << 3) + (hi << 2);
        int col = (tl << 5) + lo;
        Go[(row << 7) + col] = ftoh(acc[tl][rg] * scale);
      }
  }
}

// ==================== 2. fused attention — 80KB LDS, 2 blocks/CU ===========
// S^T layout; T overwrites ELN in place; A-fragments prefetched to registers.
__global__ __launch_bounds__(512) void k_attn_fused(
    const ushort* __restrict__ emb16, const ushort* __restrict__ GtAll,
    const int* __restrict__ cnt, const int* __restrict__ lst,
    const float* __restrict__ bst, const float* __restrict__ bsi,
    float* __restrict__ BRt, float* __restrict__ BRi) {
  int r = blockIdx.x, h = blockIdx.y, set = blockIdx.z;
  int g = set * R_ + r;
  int L = cnt[g];
  if (L == 0) return;
  __shared__ __align__(16) ushort ELN[256 * 128];   // 64KB: ELN, then T in place
  __shared__ __align__(16) ushort scratch[8192];    // 16KB: Gt k-half stage
  int t = threadIdx.x;
  int w = t >> 6, l = t & 63, lo = l & 31, hi = l >> 5;

  // ---- stage ELN (swizzled) + Gt k-half 0 ----
  const uint4* Ep = (const uint4*)(emb16 + ((size_t)r << 15));
  for (int c = t; c < 4096; c += 512) {
    int n = c >> 4, s = c & 15;
    uint4 v = Ep[c];
    *(uint4*)&ELN[(n << 7) + ((s << 3) ^ ((n & 15) << 3))] = v;
  }
  const ushort* Gp = GtAll + ((size_t)(set * H_ + h) << 14);
  for (int j = t; j < 1024; j += 512) {
    int f = j >> 3, c = j & 7;
    uint4 v = *(const uint4*)(Gp + (f << 7) + (c << 3));
    *(uint4*)&scratch[(f << 6) + ((c ^ (f & 7)) << 3)] = v;
  }
  __syncthreads();   // B1

  // ---- prefetch own A-rows (rows w*32+lo) — used by BOTH GEMMs ----
  int n = (w << 5) + lo;
  f16x8 aF[8];
  #pragma unroll
  for (int ks = 0; ks < 8; ++ks)
    aF[ks] = *(const f16x8*)&ELN[(n << 7) + (((ks << 4) + (hi << 3)) ^ ((n & 15) << 3))];

  // ---- T = ELN * Gt, k-half 0 ----
  f32x16 tacc[4];
  #pragma unroll
  for (int i = 0; i < 4; ++i)
    #pragma unroll
    for (int j = 0; j < 16; ++j) tacc[i][j] = 0.0f;
  #pragma unroll
  for (int ksl = 0; ksl < 4; ++ksl) {
    #pragma unroll
    for (int tl = 0; tl < 4; ++tl) {
      int f = (tl << 5) + lo;
      f16x8 b = *(const f16x8*)&scratch[(f << 6) + ((((ksl << 1) + hi) ^ (f & 7)) << 3)];
      tacc[tl] = __builtin_amdgcn_mfma_f32_32x32x16_f16(aF[ksl], b, tacc[tl], 0, 0, 0);
    }
  }
  __syncthreads();   // B2: half-0 reads done
  for (int j = t; j < 1024; j += 512) {   // stage Gt k-half 1
    int f = j >> 3, c = j & 7;
    uint4 v = *(const uint4*)(Gp + (f << 7) + 64 + (c << 3));
    *(uint4*)&scratch[(f << 6) + ((c ^ (f & 7)) << 3)] = v;
  }
  __syncthreads();   // B3
  #pragma unroll
  for (int ksl = 0; ksl < 4; ++ksl) {
    #pragma unroll
    for (int tl = 0; tl < 4; ++tl) {
      int f = (tl << 5) + lo;
      f16x8 b = *(const f16x8*)&scratch[(f << 6) + ((((ksl << 1) + hi) ^ (f & 7)) << 3)];
      tacc[tl] = __builtin_amdgcn_mfma_f32_32x32x16_f16(aF[4 + ksl], b, tacc[tl], 0, 0, 0);
    }
  }

  // ---- write T over ELN (own rows only; ELN fully consumed already) ----
  #pragma unroll
  for (int tl = 0; tl < 4; ++tl)
    #pragma unroll
    for (int rg = 0; rg < 16; ++rg) {
      int row = (w << 5) + (rg & 3) + ((rg >> 2) << 3) + (hi << 2);
      int col = (tl << 5) + lo;
      ELN[(row << 7) + (col ^ ((row & 15) << 3))] = ftoh(tacc[tl][rg]);
    }
  __syncthreads();   // B4: T visible to all waves

  // ---- S^T[m,n] : A = aF (own rows m), B = T rows (all 256 n) ----
  f32x16 acc[8];
  #pragma unroll
  for (int i = 0; i < 8; ++i)
    #pragma unroll
    for (int j = 0; j < 16; ++j) acc[i][j] = 0.0f;
  #pragma unroll
  for (int ks = 0; ks < 8; ++ks) {
    #pragma unroll
    for (int tl = 0; tl < 8; ++tl) {
      int nn = (tl << 5) + lo;
      f16x8 b = *(const f16x8*)&ELN[(nn << 7) + (((ks << 4) + (hi << 3)) ^ ((nn & 15) << 3))];
      acc[tl] = __builtin_amdgcn_mfma_f32_32x32x16_f16(aF[ks], b, acc[tl], 0, 0, 0);
    }
  }

  // ---- wave-local softmax over n (8 regs x 32 lo-lanes) ----
  float den[16];
  #pragma unroll
  for (int rg = 0; rg < 16; ++rg) {
    float mx = acc[0][rg];
    #pragma unroll
    for (int tl = 1; tl < 8; ++tl) mx = fmaxf(mx, acc[tl][rg]);
    #pragma unroll
    for (int off = 16; off > 0; off >>= 1) mx = fmaxf(mx, __shfl_xor(mx, off));
    float s = 0.0f;
    #pragma unroll
    for (int tl = 0; tl < 8; ++tl) {
      acc[tl][rg] = __expf(acc[tl][rg] - mx);
      s += acc[tl][rg];
    }
    #pragma unroll
    for (int off = 16; off > 0; off >>= 1) s += __shfl_xor(s, off);
    den[rg] = s;
  }

  // ---- BR for each l in this r's group (register dot + shuffles) ----
  const float* wv = set ? bsi : bst;
  float* BR = set ? BRi : BRt;
  for (int li = 0; li < L; ++li) {
    int ll = lst[g * 64 + li];
    const float* wr = wv + (size_t)ll * N_;
    float bw[8];
    #pragma unroll
    for (int tl = 0; tl < 8; ++tl) bw[tl] = wr[(tl << 5) + lo];
    #pragma unroll
    for (int rg = 0; rg < 16; ++rg) {
      float p = 0.0f;
      #pragma unroll
      for (int tl = 0; tl < 8; ++tl) p += bw[tl] * acc[tl][rg];
      #pragma unroll
      for (int off = 16; off > 0; off >>= 1) p += __shfl_xor(p, off);
      if (lo == 0) {
        int m = (w << 5) + (rg & 3) + ((rg >> 2) << 3) + (hi << 2);
        BR[((size_t)ll * N_ + m) * H_ + h] = p / den[rg];
      }
    }
  }
}

// ==================== 3. BS + CS + OS, with per-block LN partials ==========
__global__ __launch_bounds__(256) void k_bscs_os(
    const float* __restrict__ BRt, const float* __restrict__ BRi,
    const float* __restrict__ Ssq, const float* __restrict__ Tsq,
    const float* __restrict__ emb, const float* __restrict__ projb,
    float* __restrict__ outBS, float* __restrict__ outCS,
    float* __restrict__ outOS,
    float2* __restrict__ pBS, float2* __restrict__ pCS,
    float2* __restrict__ pOS) {
  __shared__ float pr[8][E_];
  __shared__ float rb[4][4];
  int bid = blockIdx.x, t = threadIdx.x;
  if (bid < 1600) {
    int i = bid * 256 + t;
    int n = i & 255, c = (i >> 8) & 63, l = i >> 14;
    const float4* a = (const float4*)&BRt[((size_t)l * N_ + n) * H_];
    const float4* b = (const float4*)&BRi[((size_t)c * N_ + n) * H_];
    float4 a0 = a[0], a1 = a[1], b0 = b[0], b1 = b[1];
    float dot = a0.x * b0.x + a0.y * b0.y + a0.z * b0.z + a0.w * b0.w
              + a1.x * b1.x + a1.y * b1.y + a1.z * b1.z + a1.w * b1.w;
    float na = a0.x * a0.x + a0.y * a0.y + a0.z * a0.z + a0.w * a0.w
             + a1.x * a1.x + a1.y * a1.y + a1.z * a1.z + a1.w * a1.w;
    float nb = b0.x * b0.x + b0.y * b0.y + b0.z * b0.z + b0.w * b0.w
             + b1.x * b1.x + b1.y * b1.y + b1.z * b1.z + b1.w * b1.w;
    float bsv = dot / fmaxf(sqrtf(na) * sqrtf(nb), 1e-15f);
    outBS[i] = bsv;

    const float4* sp = (const float4*)&Ssq[((size_t)l * N_ + n) * SQS];
    const float4* tp = (const float4*)&Tsq[((size_t)c * N_ + n) * SQS];
    float d2 = 0.0f;
    #pragma unroll
    for (int j = 0; j < 7; ++j) {
      float4 sv = sp[j], tv = tp[j];
      d2 += sv.x * tv.x + sv.y * tv.y + sv.z * tv.z + sv.w * tv.w;
    }
    float csv = logf(d2) * (1.0f / 27.0f);
    outCS[i] = csv;
    float s0 = waveReduceSum(bsv), q0 = waveReduceSum(bsv * bsv);
    float s1 = waveReduceSum(csv), q1 = waveReduceSum(csv * csv);
    if ((t & 63) == 0) {
      int wv = t >> 6;
      rb[wv][0] = s0; rb[wv][1] = q0; rb[wv][2] = s1; rb[wv][3] = q1;
    }
    __syncthreads();
    if (t == 0) {
      float A = 0, B = 0, Cq = 0, D = 0;
      #pragma unroll
      for (int k = 0; k < 4; ++k) { A += rb[k][0]; B += rb[k][1]; Cq += rb[k][2]; D += rb[k][3]; }
      pBS[bid] = make_float2(A, B);
      pCS[bid] = make_float2(Cq, D);
    }
  } else {
    int o = bid - 1600;
    int l = o >> 3, cg = o & 7;
    for (int i = t; i < 1024; i += 256)
      pr[i >> 7][i & 127] = projb[(cg * 8 + (i >> 7)) * E_ + (i & 127)];
    __syncthreads();
    const float* er = &emb[((size_t)(l * N_) + t) << 7];
    float acc[8] = {0, 0, 0, 0, 0, 0, 0, 0};
    for (int e = 0; e < 128; e += 4) {
      float4 v = *(const float4*)&er[e];
      #pragma unroll
      for (int c = 0; c < 8; ++c)
        acc[c] += v.x * pr[c][e] + v.y * pr[c][e + 1] + v.z * pr[c][e + 2] + v.w * pr[c][e + 3];
    }
    float s = 0.0f, q = 0.0f;
    #pragma unroll
    for (int c = 0; c < 8; ++c) {
      outOS[((size_t)l * C_ + cg * 8 + c) * N_ + t] = acc[c];
      s += acc[c];
      q += acc[c] * acc[c];
    }
    s = waveReduceSum(s);
    q = waveReduceSum(q);
    if ((t & 63) == 0) { int wv = t >> 6; rb[wv][0] = s; rb[wv][1] = q; }
    __syncthreads();
    if (t == 0) {
      float A = 0, B = 0;
      #pragma unroll
      for (int k = 0; k < 4; ++k) { A += rb[k][0]; B += rb[k][1]; }
      pOS[o] = make_float2(A, B);
    }
  }
}

// ==================== 4. LN apply (single pass, stats from partials) =======
__global__ __launch_bounds__(256) void k_ln_apply(
    float* __restrict__ out,
    const float2* __restrict__ pBS, const float2* __restrict__ pCS,
    const float2* __restrict__ pOS,
    const float* __restrict__ w0, const float* __restrict__ b0,
    const float* __restrict__ w1, const float* __restrict__ b1,
    const float* __restrict__ w2, const float* __restrict__ b2) {
  int r = blockIdx.x, o = blockIdx.y, chunk = blockIdx.z;   // (25,3,8)
  int t = threadIdx.x;
  __shared__ float sm[2];
  if (t < 64) {
    float s = 0.0f, q = 0.0f;
    if (o == 2) {
      if (t < 8) { float2 v = pOS[r * 8 + t]; s = v.x; q = v.y; }
    } else {
      const float2* pp = (o == 0) ? pBS : pCS;
      float2 v = pp[r * 64 + t]; s = v.x; q = v.y;
    }
    #pragma unroll
    for (int off = 32; off > 0; off >>= 1) {
      s += __shfl_xor(s, off);
      q += __shfl_xor(q, off);
    }
    if (t == 0) {
      float m = s * (1.0f / 16384.0f);
      float v = q * (1.0f / 16384.0f) - m * m;
      sm[0] = m;
      sm[1] = 1.0f / sqrtf(v + 1e-5f);
    }
  }
  __syncthreads();
  float m = sm[0], inv = sm[1];
  const float* w = (o == 0) ? w0 : (o == 1) ? w1 : w2;
  const float* b = (o == 0) ? b0 : (o == 1) ? b1 : b2;
  float* x = out + (size_t)o * 409600 + (size_t)r * 16384;
  int base = chunk * 2048;
  #pragma unroll
  for (int k = 0; k < 8; ++k) {
    int pos = base + k * 256 + t;
    x[pos] = (x[pos] - m) * inv * w[pos] + b[pos];
  }
}

// ==================== host launcher ========================================
extern "C" void kernel_launch(void* const* d_in, const int* in_sizes, int n_in,
                              void* d_out, int out_size, void* d_ws, size_t ws_size,
                              hipStream_t stream) {
  const float* bus_t  = (const float*)d_in[0];
  const float* bus_i  = (const float*)d_in[1];
  const float* cus_t  = (const float*)d_in[2];
  const float* cus_i  = (const float*)d_in[3];
  const int*   idx_t  = (const int*)d_in[4];
  const int*   idx_i  = (const int*)d_in[5];
  const int*   cov    = (const int*)d_in[6];
  const float* emb    = (const float*)d_in[7];
  const float* ln_w   = (const float*)d_in[8];
  const float* ln_b   = (const float*)d_in[9];
  const float* WQ_trg = (const float*)d_in[10];
  const float* WK_trg = (const float*)d_in[11];
  const float* WQ_inf = (const float*)d_in[12];
  const float* WK_inf = (const float*)d_in[13];
  const float* W_os   = (const float*)d_in[14];
  const float* b_os   = (const float*)d_in[15];
  const float* bs_w   = (const float*)d_in[16];
  const float* bs_b   = (const float*)d_in[17];
  const float* cs_w   = (const float*)d_in[18];
  const float* cs_b   = (const float*)d_in[19];
  const float* os_w   = (const float*)d_in[20];
  const float* os_b   = (const float*)d_in[21];

  float* ws = (float*)d_ws;
  ushort* emb16 = (ushort*)ws;                 // 409600 f32 slots
  float* p = ws + 409600;
  ushort* Gt = (ushort*)p;   p += 131072;      // 16 x 128 x 128 f16
  float* bst = p;            p += 6400;
  float* bsi = p;            p += 16384;
  float* Ssq = p;            p += R_ * N_ * SQS;   // 179200
  float* Tsq = p;            p += C_ * N_ * SQS;   // 458752
  float* BRt = p;            p += 51200;
  float* BRi = p;            p += 131072;
  float* projb = p;          p += 8192;
  int* cnt = (int*)p;        p += 64;
  int* lst = (int*)p;        p += 3200;
  float2* pBS = (float2*)p;  p += 3200;
  float2* pCS = (float2*)p;  p += 3200;
  float2* pOS = (float2*)p;  p += 400;

  float* outBS = (float*)d_out;
  float* outCS = outBS + 409600;
  float* outOS = outCS + 409600;

  k_prep<<<2094, 256, 0, stream>>>(emb, ln_w, ln_b, emb16,
                                   bus_t, bus_i, bst, bsi,
                                   cus_t, cus_i, Ssq, Tsq,
                                   idx_t, idx_i, cnt, lst,
                                   cov, W_os, b_os, projb,
                                   WQ_trg, WK_trg, WQ_inf, WK_inf, Gt);
  k_attn_fused<<<dim3(R_, H_, 2), 512, 0, stream>>>(emb16, Gt, cnt, lst,
                                                    bst, bsi, BRt, BRi);
  k_bscs_os<<<1800, 256, 0, stream>>>(BRt, BRi, Ssq, Tsq, emb, projb,
                                      outBS, outCS, outOS, pBS, pCS, pOS);
  k_ln_apply<<<dim3(R_, 3, 8), 256, 0, stream>>>(outBS, pBS, pCS, pOS,
                                                 bs_w, bs_b, cs_w, cs_b, os_w, os_b);
}

// Round 13
// 82.160 us; speedup vs baseline: 1.2150x; 1.2150x over previous
//
#include <hip/hip_runtime.h>
#include <math.h>

#define R_ 25
#define N_ 256
#define C_ 64
#define E_ 128
#define H_ 8
#define NC_ 27
#define SQS 28   // padded row stride for sqrt-softmax tables

typedef _Float16 f16x8 __attribute__((ext_vector_type(8)));
typedef float f32x16 __attribute__((ext_vector_type(16)));

union HU { ushort s; _Float16 h; };
__device__ __forceinline__ ushort ftoh(float f) { HU u; u.h = (_Float16)f; return u.s; }
__device__ __forceinline__ float htof(ushort s) { HU u; u.s = s; return (float)u.h; }

__device__ __forceinline__ float waveReduceSum(float v) {
  #pragma unroll
  for (int off = 32; off > 0; off >>= 1) v += __shfl_xor(v, off);
  return v;
}

// ==================== 1. PREP ==============================================
// grid: [0,1600) emb_ln | [1600,1689) mean4 | [1689,2045) sqsm (4 lanes/row)
//       2045 groups | [2046,2078) os-proj | [2078,2094) Gt MFMA
__global__ __launch_bounds__(256) void k_prep(
    const float* __restrict__ emb, const float* __restrict__ ln_w,
    const float* __restrict__ ln_b, ushort* __restrict__ emb16,
    const float* __restrict__ bus_t, const float* __restrict__ bus_i,
    float* __restrict__ bst, float* __restrict__ bsi,
    const float* __restrict__ cus_t, const float* __restrict__ cus_i,
    float* __restrict__ Ssq, float* __restrict__ Tsq,
    const int* __restrict__ idx_t, const int* __restrict__ idx_i,
    int* __restrict__ cnt, int* __restrict__ lst,
    const int* __restrict__ biz, const float* __restrict__ Wos,
    const float* __restrict__ bos, float* __restrict__ projb,
    const float* __restrict__ WQt_, const float* __restrict__ WKt_,
    const float* __restrict__ WQi_, const float* __restrict__ WKi_,
    ushort* __restrict__ Gt) {
  __shared__ uint sbuf[16384];   // 64KB, reused per branch
  int bid = blockIdx.x, t = threadIdx.x;
  if (bid < 1600) {
    // ---- emb layernorm -> f16, 4 rows/block ----
    int row = bid * 4 + (t >> 6);
    int lane = t & 63;
    const float2* x = (const float2*)(emb + (size_t)row * E_);
    float2 v = x[lane];
    float s = waveReduceSum(v.x + v.y);
    float m = s * (1.0f / 128.0f);
    float d0 = v.x - m, d1 = v.y - m;
    float ss = waveReduceSum(d0 * d0 + d1 * d1);
    float inv = 1.0f / sqrtf(ss * (1.0f / 128.0f) + 1e-16f);
    float2 wv = ((const float2*)ln_w)[lane];
    float2 bv = ((const float2*)ln_b)[lane];
    uint u = (uint)ftoh(d0 * inv * wv.x + bv.x) | ((uint)ftoh(d1 * inv * wv.y + bv.y) << 16);
    ((uint*)emb16)[(size_t)row * 64 + lane] = u;
  } else if (bid < 1689) {
    // ---- mean over trailing 4 ----
    int i = (bid - 1600) * 256 + t;
    if (i < R_ * N_) {
      size_t row = (size_t)(i >> 8) * (C_ * N_) + (i & 255);
      float4 v = *(const float4*)&bus_t[row * 4];
      bst[i] = (v.x + v.y + v.z + v.w) * 0.25f;
    }
    int j = i - R_ * N_;
    if (j >= 0 && j < C_ * N_) {
      float4 v = *(const float4*)&bus_i[(size_t)j * 4];
      bsi[j] = (v.x + v.y + v.z + v.w) * 0.25f;
    }
  } else if (bid < 2045) {
    // ---- sqrt(softmax(mean4 over 27)), 4 lanes per row ----
    int gidx = (bid - 1689) * 256 + t;
    int rowi = gidx >> 2, sub = gidx & 3;
    const float* src; float* dst; size_t base; int oi;
    if (rowi < R_ * N_) {
      src = cus_t; dst = Ssq; oi = rowi;
      base = ((size_t)(rowi >> 8) * (C_ * N_) + (rowi & 255)) * (NC_ * 4);
    } else {
      int j = rowi - R_ * N_;
      if (j >= C_ * N_) return;
      src = cus_i; dst = Tsq; oi = j;
      base = ((size_t)(j >> 8) * N_ + (j & 255)) * (NC_ * 4);
    }
    int j0 = sub * 7;
    int nj = (sub == 3) ? 6 : 7;
    float v[7];
    float mx = -1e30f;
    #pragma unroll
    for (int k = 0; k < 7; ++k) {
      if (k < nj) {
        float4 q = *(const float4*)&src[base + (j0 + k) * 4];
        v[k] = (q.x + q.y + q.z + q.w) * 0.25f;
        mx = fmaxf(mx, v[k]);
      }
    }
    mx = fmaxf(mx, __shfl_xor(mx, 1));
    mx = fmaxf(mx, __shfl_xor(mx, 2));
    float se = 0.0f;
    #pragma unroll
    for (int k = 0; k < 7; ++k) if (k < nj) se += expf(v[k] - mx);
    se += __shfl_xor(se, 1);
    se += __shfl_xor(se, 2);
    float lse = mx + logf(se);
    #pragma unroll
    for (int k = 0; k < 7; ++k)
      if (k < nj) dst[(size_t)oi * SQS + j0 + k] = expf(0.5f * (v[k] - lse));
    if (sub == 3) dst[(size_t)oi * SQS + NC_] = 0.0f;
  } else if (bid == 2045) {
    // ---- group lists ----
    if (t < 2 * R_) cnt[t] = 0;
    __syncthreads();
    if (t < R_) {
      int rr = idx_t[t * C_];
      int pos = atomicAdd(&cnt[rr], 1);
      lst[rr * 64 + pos] = t;
    }
    if (t < C_) {
      int rr = idx_i[t];
      int pos = atomicAdd(&cnt[R_ + rr], 1);
      lst[(R_ + rr) * 64 + pos] = t;
    }
  } else if (bid < 2078) {
    // ---- OS projection: proj[c][f] = emb[row_c] . Wos[f] + bos[f], 2 c/block ----
    float* er2 = (float*)sbuf;    // [2][128]
    int pb = bid - 2046;
    int ci = t >> 7, f = t & 127;
    int c = pb * 2 + ci;
    int row = idx_i[c] * N_ + biz[c];
    er2[ci * E_ + f] = emb[(size_t)row * E_ + f];
    __syncthreads();
    float acc = bos[f];
    const float* wr = &Wos[(size_t)f * E_];
    const float* er = &er2[ci * E_];
    for (int e = 0; e < E_; e += 4) {
      float4 w4 = *(const float4*)&wr[e];
      acc += er[e] * w4.x + er[e + 1] * w4.y + er[e + 2] * w4.z + er[e + 3] * w4.w;
    }
    projb[c * E_ + f] = acc;
  } else {
    // ---- Gt[set,h][e'][e] = sum_f WK[h,f,e']*WQ[h,f,e]/sqrt(E), MFMA ----
    int gb = bid - 2078;
    int h = gb & 7, set = gb >> 3;
    const float* WQ = (set ? WQi_ : WQt_) + ((size_t)h << 14);
    const float* WK = (set ? WKi_ : WKt_) + ((size_t)h << 14);
    uint* QT = sbuf;          // [e][f2 swz]
    uint* KT = sbuf + 8192;   // [e'][f2 swz]
    for (int j = t; j < 8192; j += 256) {
      int e = j & 127, f2 = j >> 7;
      int wi = (f2 << 8) + e;
      float q0 = WQ[wi], q1 = WQ[wi + 128];
      float k0 = WK[wi], k1 = WK[wi + 128];
      int idx = (e << 6) + (f2 ^ ((e & 15) << 2));
      QT[idx] = (uint)ftoh(q0) | ((uint)ftoh(q1) << 16);
      KT[idx] = (uint)ftoh(k0) | ((uint)ftoh(k1) << 16);
    }
    __syncthreads();
    int w = t >> 6, l = t & 63, lo = l & 31, hi = l >> 5;
    int m0 = w << 5;
    f32x16 acc[4];
    #pragma unroll
    for (int i = 0; i < 4; ++i)
      #pragma unroll
      for (int j = 0; j < 16; ++j) acc[i][j] = 0.0f;
    int mrow = m0 + lo;
    #pragma unroll
    for (int ks = 0; ks < 8; ++ks) {
      int f2b = (ks << 3) + (hi << 2);
      f16x8 a = *(const f16x8*)&KT[(mrow << 6) + (f2b ^ ((mrow & 15) << 2))];
      #pragma unroll
      for (int tl = 0; tl < 4; ++tl) {
        int ncol = (tl << 5) + lo;
        f16x8 b = *(const f16x8*)&QT[(ncol << 6) + (f2b ^ ((ncol & 15) << 2))];
        acc[tl] = __builtin_amdgcn_mfma_f32_32x32x16_f16(a, b, acc[tl], 0, 0, 0);
      }
    }
    const float scale = 0.08838834764831845f;   // 1/sqrt(128)
    ushort* Go = Gt + (((size_t)(set * H_ + h)) << 14);
    #pragma unroll
    for (int tl = 0; tl < 4; ++tl)
      #pragma unroll
      for (int rg = 0; rg < 16; ++rg) {
        int row = m0 + (rg & 3) + ((rg >> 2) << 3) + (hi << 2);
        int col = (tl << 5) + lo;
        Go[(row << 7) + col] = ftoh(acc[tl][rg] * scale);
      }
  }
}

// ==================== 2. fused attention (R6 path, sets merged) ============
// grid (25, 8): ELN staged once per (r,h); loop set in {0,1} staging only Gt.
__global__ __launch_bounds__(512) void k_attn_fused(
    const ushort* __restrict__ emb16, const ushort* __restrict__ GtAll,
    const int* __restrict__ cnt, const int* __restrict__ lst,
    const float* __restrict__ bst, const float* __restrict__ bsi,
    float* __restrict__ BRt, float* __restrict__ BRi) {
  int r = blockIdx.x, h = blockIdx.y;
  int L0 = cnt[r], L1 = cnt[R_ + r];
  if (L0 == 0 && L1 == 0) return;
  __shared__ ushort ELN[256 * 128];   // 64KB (staged once)
  __shared__ ushort TA[128 * 128];    // Gt stage, then T rows 0..127
  __shared__ ushort TB[128 * 128];    // T rows 128..255
  __shared__ float redA[8 * 128];
  __shared__ float redB[8 * 128];
  __shared__ float gM[128], gD[128];
  int t = threadIdx.x;
  int w = t >> 6, l = t & 63, lo = l & 31, hi = l >> 5;
  int n = (w << 5) + lo;
  int rrow = n & 127;
  int baseRow = (w << 5) + (hi << 2);

  // ---- stage ELN (swizzled) once: shared by both sets ----
  const uint4* Ep = (const uint4*)(emb16 + ((size_t)r << 15));
  for (int c = t; c < 4096; c += 512) {
    int nn = c >> 4, s = c & 15;
    uint4 v = Ep[c];
    *(uint4*)&ELN[(nn << 7) + ((s << 3) ^ ((nn & 15) << 3))] = v;
  }

  for (int set = 0; set < 2; ++set) {
    int L = set ? L1 : L0;
    if (L == 0) continue;
    int g = set * R_ + r;
    // ---- stage Gt (swizzled) into TA ----
    const uint4* Gp = (const uint4*)(GtAll + ((size_t)(set * H_ + h) << 14));
    for (int c = t; c < 2048; c += 512) {
      int e2 = c >> 4, s = c & 15;
      uint4 v = Gp[c];
      *(uint4*)&TA[(e2 << 7) + ((s << 3) ^ ((e2 & 15) << 3))] = v;
    }
    __syncthreads();
    // ---- T = ELN * Gt ----
    f32x16 tacc[4];
    #pragma unroll
    for (int i = 0; i < 4; ++i)
      #pragma unroll
      for (int j = 0; j < 16; ++j) tacc[i][j] = 0.0f;
    #pragma unroll
    for (int ks = 0; ks < 8; ++ks) {
      f16x8 a = *(const f16x8*)&ELN[(n << 7) + (((ks << 4) + (hi << 3)) ^ ((n & 15) << 3))];
      #pragma unroll
      for (int tl = 0; tl < 4; ++tl) {
        int f = (tl << 5) + lo;
        f16x8 b = *(const f16x8*)&TA[(f << 7) + (((ks << 4) + (hi << 3)) ^ ((f & 15) << 3))];
        tacc[tl] = __builtin_amdgcn_mfma_f32_32x32x16_f16(a, b, tacc[tl], 0, 0, 0);
      }
    }
    __syncthreads();   // all waves done reading Gt from TA
    {
      ushort* Tl = (w < 4) ? TA : TB;
      #pragma unroll
      for (int tl = 0; tl < 4; ++tl)
        #pragma unroll
        for (int rg = 0; rg < 16; ++rg) {
          int row = ((w & 3) << 5) + (rg & 3) + ((rg >> 2) << 3) + (hi << 2);
          int col = (tl << 5) + lo;
          Tl[(row << 7) + (col ^ ((row & 15) << 3))] = ftoh(tacc[tl][rg]);
        }
    }
    __syncthreads();
    const float* wv = set ? bsi : bst;
    float* BR = set ? BRi : BRt;
    const ushort* Tl = (w < 4) ? TA : TB;
    for (int mh = 0; mh < 2; ++mh) {
      f32x16 acc[4];
      #pragma unroll
      for (int i = 0; i < 4; ++i)
        #pragma unroll
        for (int j = 0; j < 16; ++j) acc[i][j] = 0.0f;
      #pragma unroll
      for (int ks = 0; ks < 8; ++ks) {
        f16x8 a = *(const f16x8*)&Tl[(rrow << 7) + (((ks << 4) + (hi << 3)) ^ ((rrow & 15) << 3))];
        #pragma unroll
        for (int tl = 0; tl < 4; ++tl) {
          int m = (mh << 7) + (tl << 5) + lo;
          f16x8 b = *(const f16x8*)&ELN[(m << 7) + (((ks << 4) + (hi << 3)) ^ ((m & 15) << 3))];
          acc[tl] = __builtin_amdgcn_mfma_f32_32x32x16_f16(a, b, acc[tl], 0, 0, 0);
        }
      }
      #pragma unroll
      for (int tl = 0; tl < 4; ++tl) {
        float mx = acc[tl][0];
        #pragma unroll
        for (int rg = 1; rg < 16; ++rg) mx = fmaxf(mx, acc[tl][rg]);
        mx = fmaxf(mx, __shfl_xor(mx, 32));
        if (hi == 0) redA[(w << 7) + (tl << 5) + lo] = mx;
      }
      __syncthreads();
      if (t < 128) {
        float gm = redA[t];
        #pragma unroll
        for (int ww = 1; ww < 8; ++ww) gm = fmaxf(gm, redA[(ww << 7) + t]);
        gM[t] = gm;
      }
      __syncthreads();
      #pragma unroll
      for (int tl = 0; tl < 4; ++tl) {
        float gmv = gM[(tl << 5) + lo];
        float s = 0.0f;
        #pragma unroll
        for (int rg = 0; rg < 16; ++rg) {
          acc[tl][rg] = __expf(acc[tl][rg] - gmv);
          s += acc[tl][rg];
        }
        s += __shfl_xor(s, 32);
        if (hi == 0) redB[(w << 7) + (tl << 5) + lo] = s;
      }
      __syncthreads();
      if (t < 128) {
        float d = 0.0f;
        #pragma unroll
        for (int ww = 0; ww < 8; ++ww) d += redB[(ww << 7) + t];
        gD[t] = d;
      }
      __syncthreads();
      for (int li = 0; li < L; ++li) {
        int ll = lst[g * 64 + li];
        float wreg[16];
        #pragma unroll
        for (int rg = 0; rg < 16; ++rg)
          wreg[rg] = wv[ll * N_ + baseRow + (rg & 3) + ((rg >> 2) << 3)];
        #pragma unroll
        for (int tl = 0; tl < 4; ++tl) {
          float part = 0.0f;
          #pragma unroll
          for (int rg = 0; rg < 16; ++rg) part += wreg[rg] * acc[tl][rg];
          part += __shfl_xor(part, 32);
          if (hi == 0) redA[(w << 7) + (tl << 5) + lo] = part;
        }
        __syncthreads();
        if (t < 128) {
          float s = 0.0f;
          #pragma unroll
          for (int ww = 0; ww < 8; ++ww) s += redA[(ww << 7) + t];
          BR[((size_t)ll * N_ + (mh << 7) + t) * H_ + h] = s / gD[t];
        }
        __syncthreads();
      }
    }
  }
}

// ==================== 3. BS + CS + OS, with per-block LN partials ==========
__global__ __launch_bounds__(256) void k_bscs_os(
    const float* __restrict__ BRt, const float* __restrict__ BRi,
    const float* __restrict__ Ssq, const float* __restrict__ Tsq,
    const float* __restrict__ emb, const float* __restrict__ projb,
    float* __restrict__ outBS, float* __restrict__ outCS,
    float* __restrict__ outOS,
    float2* __restrict__ pBS, float2* __restrict__ pCS,
    float2* __restrict__ pOS) {
  __shared__ float pr[8][E_];
  __shared__ float rb[4][4];
  int bid = blockIdx.x, t = threadIdx.x;
  if (bid < 1600) {
    int i = bid * 256 + t;
    int n = i & 255, c = (i >> 8) & 63, l = i >> 14;
    const float4* a = (const float4*)&BRt[((size_t)l * N_ + n) * H_];
    const float4* b = (const float4*)&BRi[((size_t)c * N_ + n) * H_];
    float4 a0 = a[0], a1 = a[1], b0 = b[0], b1 = b[1];
    float dot = a0.x * b0.x + a0.y * b0.y + a0.z * b0.z + a0.w * b0.w
              + a1.x * b1.x + a1.y * b1.y + a1.z * b1.z + a1.w * b1.w;
    float na = a0.x * a0.x + a0.y * a0.y + a0.z * a0.z + a0.w * a0.w
             + a1.x * a1.x + a1.y * a1.y + a1.z * a1.z + a1.w * a1.w;
    float nb = b0.x * b0.x + b0.y * b0.y + b0.z * b0.z + b0.w * b0.w
             + b1.x * b1.x + b1.y * b1.y + b1.z * b1.z + b1.w * b1.w;
    float bsv = dot / fmaxf(sqrtf(na) * sqrtf(nb), 1e-15f);
    outBS[i] = bsv;

    const float4* sp = (const float4*)&Ssq[((size_t)l * N_ + n) * SQS];
    const float4* tp = (const float4*)&Tsq[((size_t)c * N_ + n) * SQS];
    float d2 = 0.0f;
    #pragma unroll
    for (int j = 0; j < 7; ++j) {
      float4 sv = sp[j], tv = tp[j];
      d2 += sv.x * tv.x + sv.y * tv.y + sv.z * tv.z + sv.w * tv.w;
    }
    float csv = logf(d2) * (1.0f / 27.0f);
    outCS[i] = csv;
    float s0 = waveReduceSum(bsv), q0 = waveReduceSum(bsv * bsv);
    float s1 = waveReduceSum(csv), q1 = waveReduceSum(csv * csv);
    if ((t & 63) == 0) {
      int wv = t >> 6;
      rb[wv][0] = s0; rb[wv][1] = q0; rb[wv][2] = s1; rb[wv][3] = q1;
    }
    __syncthreads();
    if (t == 0) {
      float A = 0, B = 0, Cq = 0, D = 0;
      #pragma unroll
      for (int k = 0; k < 4; ++k) { A += rb[k][0]; B += rb[k][1]; Cq += rb[k][2]; D += rb[k][3]; }
      pBS[bid] = make_float2(A, B);
      pCS[bid] = make_float2(Cq, D);
    }
  } else {
    int o = bid - 1600;
    int l = o >> 3, cg = o & 7;
    for (int i = t; i < 1024; i += 256)
      pr[i >> 7][i & 127] = projb[(cg * 8 + (i >> 7)) * E_ + (i & 127)];
    __syncthreads();
    const float* er = &emb[((size_t)(l * N_) + t) << 7];
    float acc[8] = {0, 0, 0, 0, 0, 0, 0, 0};
    for (int e = 0; e < 128; e += 4) {
      float4 v = *(const float4*)&er[e];
      #pragma unroll
      for (int c = 0; c < 8; ++c)
        acc[c] += v.x * pr[c][e] + v.y * pr[c][e + 1] + v.z * pr[c][e + 2] + v.w * pr[c][e + 3];
    }
    float s = 0.0f, q = 0.0f;
    #pragma unroll
    for (int c = 0; c < 8; ++c) {
      outOS[((size_t)l * C_ + cg * 8 + c) * N_ + t] = acc[c];
      s += acc[c];
      q += acc[c] * acc[c];
    }
    s = waveReduceSum(s);
    q = waveReduceSum(q);
    if ((t & 63) == 0) { int wv = t >> 6; rb[wv][0] = s; rb[wv][1] = q; }
    __syncthreads();
    if (t == 0) {
      float A = 0, B = 0;
      #pragma unroll
      for (int k = 0; k < 4; ++k) { A += rb[k][0]; B += rb[k][1]; }
      pOS[o] = make_float2(A, B);
    }
  }
}

// ==================== 4. LN apply (single pass, stats from partials) =======
__global__ __launch_bounds__(256) void k_ln_apply(
    float* __restrict__ out,
    const float2* __restrict__ pBS, const float2* __restrict__ pCS,
    const float2* __restrict__ pOS,
    const float* __restrict__ w0, const float* __restrict__ b0,
    const float* __restrict__ w1, const float* __restrict__ b1,
    const float* __restrict__ w2, const float* __restrict__ b2) {
  int r = blockIdx.x, o = blockIdx.y, chunk = blockIdx.z;   // (25,3,8)
  int t = threadIdx.x;
  __shared__ float sm[2];
  if (t < 64) {
    float s = 0.0f, q = 0.0f;
    if (o == 2) {
      if (t < 8) { float2 v = pOS[r * 8 + t]; s = v.x; q = v.y; }
    } else {
      const float2* pp = (o == 0) ? pBS : pCS;
      float2 v = pp[r * 64 + t]; s = v.x; q = v.y;
    }
    #pragma unroll
    for (int off = 32; off > 0; off >>= 1) {
      s += __shfl_xor(s, off);
      q += __shfl_xor(q, off);
    }
    if (t == 0) {
      float m = s * (1.0f / 16384.0f);
      float v = q * (1.0f / 16384.0f) - m * m;
      sm[0] = m;
      sm[1] = 1.0f / sqrtf(v + 1e-5f);
    }
  }
  __syncthreads();
  float m = sm[0], inv = sm[1];
  const float* w = (o == 0) ? w0 : (o == 1) ? w1 : w2;
  const float* b = (o == 0) ? b0 : (o == 1) ? b1 : b2;
  float* x = out + (size_t)o * 409600 + (size_t)r * 16384;
  int base = chunk * 2048;
  #pragma unroll
  for (int k = 0; k < 8; ++k) {
    int pos = base + k * 256 + t;
    x[pos] = (x[pos] - m) * inv * w[pos] + b[pos];
  }
}

// ==================== host launcher ========================================
extern "C" void kernel_launch(void* const* d_in, const int* in_sizes, int n_in,
                              void* d_out, int out_size, void* d_ws, size_t ws_size,
                              hipStream_t stream) {
  const float* bus_t  = (const float*)d_in[0];
  const float* bus_i  = (const float*)d_in[1];
  const float* cus_t  = (const float*)d_in[2];
  const float* cus_i  = (const float*)d_in[3];
  const int*   idx_t  = (const int*)d_in[4];
  const int*   idx_i  = (const int*)d_in[5];
  const int*   cov    = (const int*)d_in[6];
  const float* emb    = (const float*)d_in[7];
  const float* ln_w   = (const float*)d_in[8];
  const float* ln_b   = (const float*)d_in[9];
  const float* WQ_trg = (const float*)d_in[10];
  const float* WK_trg = (const float*)d_in[11];
  const float* WQ_inf = (const float*)d_in[12];
  const float* WK_inf = (const float*)d_in[13];
  const float* W_os   = (const float*)d_in[14];
  const float* b_os   = (const float*)d_in[15];
  const float* bs_w   = (const float*)d_in[16];
  const float* bs_b   = (const float*)d_in[17];
  const float* cs_w   = (const float*)d_in[18];
  const float* cs_b   = (const float*)d_in[19];
  const float* os_w   = (const float*)d_in[20];
  const float* os_b   = (const float*)d_in[21];

  float* ws = (float*)d_ws;
  ushort* emb16 = (ushort*)ws;                 // 409600 f32 slots
  float* p = ws + 409600;
  ushort* Gt = (ushort*)p;   p += 131072;      // 16 x 128 x 128 f16
  float* bst = p;            p += 6400;
  float* bsi = p;            p += 16384;
  float* Ssq = p;            p += R_ * N_ * SQS;   // 179200
  float* Tsq = p;            p += C_ * N_ * SQS;   // 458752
  float* BRt = p;            p += 51200;
  float* BRi = p;            p += 131072;
  float* projb = p;          p += 8192;
  int* cnt = (int*)p;        p += 64;
  int* lst = (int*)p;        p += 3200;
  float2* pBS = (float2*)p;  p += 3200;
  float2* pCS = (float2*)p;  p += 3200;
  float2* pOS = (float2*)p;  p += 400;

  float* outBS = (float*)d_out;
  float* outCS = outBS + 409600;
  float* outOS = outCS + 409600;

  k_prep<<<2094, 256, 0, stream>>>(emb, ln_w, ln_b, emb16,
                                   bus_t, bus_i, bst, bsi,
                                   cus_t, cus_i, Ssq, Tsq,
                                   idx_t, idx_i, cnt, lst,
                                   cov, W_os, b_os, projb,
                                   WQ_trg, WK_trg, WQ_inf, WK_inf, Gt);
  k_attn_fused<<<dim3(R_, H_), 512, 0, stream>>>(emb16, Gt, cnt, lst,
                                                 bst, bsi, BRt, BRi);
  k_bscs_os<<<1800, 256, 0, stream>>>(BRt, BRi, Ssq, Tsq, emb, projb,
                                      outBS, outCS, outOS, pBS, pCS, pOS);
  k_ln_apply<<<dim3(R_, 3, 8), 256, 0, stream>>>(outBS, pBS, pCS, pOS,
                                                 bs_w, bs_b, cs_w, cs_b, os_w, os_b);
}

// Round 14
// 76.114 us; speedup vs baseline: 1.3116x; 1.0794x over previous
//
#include <hip/hip_runtime.h>
#include <math.h>

#define R_ 25
#define N_ 256
#define C_ 64
#define E_ 128
#define H_ 8
#define NC_ 27
#define SQS 28   // padded row stride for sqrt-softmax tables

typedef _Float16 f16x8 __attribute__((ext_vector_type(8)));
typedef float f32x16 __attribute__((ext_vector_type(16)));

union HU { ushort s; _Float16 h; };
__device__ __forceinline__ ushort ftoh(float f) { HU u; u.h = (_Float16)f; return u.s; }
__device__ __forceinline__ float htof(ushort s) { HU u; u.s = s; return (float)u.h; }

__device__ __forceinline__ float waveReduceSum(float v) {
  #pragma unroll
  for (int off = 32; off > 0; off >>= 1) v += __shfl_xor(v, off);
  return v;
}

// ==================== 1. PREP ==============================================
// grid: [0,1600) emb_ln | [1600,1689) mean4 | [1689,2045) sqsm (4 lanes/row)
//       2045 groups | [2046,2078) os-proj | [2078,2094) Gt MFMA
__global__ __launch_bounds__(256) void k_prep(
    const float* __restrict__ emb, const float* __restrict__ ln_w,
    const float* __restrict__ ln_b, ushort* __restrict__ emb16,
    const float* __restrict__ bus_t, const float* __restrict__ bus_i,
    float* __restrict__ bst, float* __restrict__ bsi,
    const float* __restrict__ cus_t, const float* __restrict__ cus_i,
    float* __restrict__ Ssq, float* __restrict__ Tsq,
    const int* __restrict__ idx_t, const int* __restrict__ idx_i,
    int* __restrict__ cnt, int* __restrict__ lst,
    const int* __restrict__ biz, const float* __restrict__ Wos,
    const float* __restrict__ bos, float* __restrict__ projb,
    const float* __restrict__ WQt_, const float* __restrict__ WKt_,
    const float* __restrict__ WQi_, const float* __restrict__ WKi_,
    ushort* __restrict__ Gt) {
  __shared__ uint sbuf[16384];   // 64KB, reused per branch
  int bid = blockIdx.x, t = threadIdx.x;
  if (bid < 1600) {
    // ---- emb layernorm -> f16, 4 rows/block ----
    int row = bid * 4 + (t >> 6);
    int lane = t & 63;
    const float2* x = (const float2*)(emb + (size_t)row * E_);
    float2 v = x[lane];
    float s = waveReduceSum(v.x + v.y);
    float m = s * (1.0f / 128.0f);
    float d0 = v.x - m, d1 = v.y - m;
    float ss = waveReduceSum(d0 * d0 + d1 * d1);
    float inv = 1.0f / sqrtf(ss * (1.0f / 128.0f) + 1e-16f);
    float2 wv = ((const float2*)ln_w)[lane];
    float2 bv = ((const float2*)ln_b)[lane];
    uint u = (uint)ftoh(d0 * inv * wv.x + bv.x) | ((uint)ftoh(d1 * inv * wv.y + bv.y) << 16);
    ((uint*)emb16)[(size_t)row * 64 + lane] = u;
  } else if (bid < 1689) {
    // ---- mean over trailing 4 ----
    int i = (bid - 1600) * 256 + t;
    if (i < R_ * N_) {
      size_t row = (size_t)(i >> 8) * (C_ * N_) + (i & 255);
      float4 v = *(const float4*)&bus_t[row * 4];
      bst[i] = (v.x + v.y + v.z + v.w) * 0.25f;
    }
    int j = i - R_ * N_;
    if (j >= 0 && j < C_ * N_) {
      float4 v = *(const float4*)&bus_i[(size_t)j * 4];
      bsi[j] = (v.x + v.y + v.z + v.w) * 0.25f;
    }
  } else if (bid < 2045) {
    // ---- sqrt(softmax(mean4 over 27)), 4 lanes per row ----
    int gidx = (bid - 1689) * 256 + t;
    int rowi = gidx >> 2, sub = gidx & 3;
    const float* src; float* dst; size_t base; int oi;
    if (rowi < R_ * N_) {
      src = cus_t; dst = Ssq; oi = rowi;
      base = ((size_t)(rowi >> 8) * (C_ * N_) + (rowi & 255)) * (NC_ * 4);
    } else {
      int j = rowi - R_ * N_;
      if (j >= C_ * N_) return;
      src = cus_i; dst = Tsq; oi = j;
      base = ((size_t)(j >> 8) * N_ + (j & 255)) * (NC_ * 4);
    }
    int j0 = sub * 7;
    int nj = (sub == 3) ? 6 : 7;
    float v[7];
    float mx = -1e30f;
    #pragma unroll
    for (int k = 0; k < 7; ++k) {
      if (k < nj) {
        float4 q = *(const float4*)&src[base + (j0 + k) * 4];
        v[k] = (q.x + q.y + q.z + q.w) * 0.25f;
        mx = fmaxf(mx, v[k]);
      }
    }
    mx = fmaxf(mx, __shfl_xor(mx, 1));
    mx = fmaxf(mx, __shfl_xor(mx, 2));
    float se = 0.0f;
    #pragma unroll
    for (int k = 0; k < 7; ++k) if (k < nj) se += expf(v[k] - mx);
    se += __shfl_xor(se, 1);
    se += __shfl_xor(se, 2);
    float lse = mx + logf(se);
    #pragma unroll
    for (int k = 0; k < 7; ++k)
      if (k < nj) dst[(size_t)oi * SQS + j0 + k] = expf(0.5f * (v[k] - lse));
    if (sub == 3) dst[(size_t)oi * SQS + NC_] = 0.0f;
  } else if (bid == 2045) {
    // ---- group lists ----
    if (t < 2 * R_) cnt[t] = 0;
    __syncthreads();
    if (t < R_) {
      int rr = idx_t[t * C_];
      int pos = atomicAdd(&cnt[rr], 1);
      lst[rr * 64 + pos] = t;
    }
    if (t < C_) {
      int rr = idx_i[t];
      int pos = atomicAdd(&cnt[R_ + rr], 1);
      lst[(R_ + rr) * 64 + pos] = t;
    }
  } else if (bid < 2078) {
    // ---- OS projection: proj[c][f] = emb[row_c] . Wos[f] + bos[f], 2 c/block ----
    float* er2 = (float*)sbuf;    // [2][128]
    int pb = bid - 2046;
    int ci = t >> 7, f = t & 127;
    int c = pb * 2 + ci;
    int row = idx_i[c] * N_ + biz[c];
    er2[ci * E_ + f] = emb[(size_t)row * E_ + f];
    __syncthreads();
    float acc = bos[f];
    const float* wr = &Wos[(size_t)f * E_];
    const float* er = &er2[ci * E_];
    for (int e = 0; e < E_; e += 4) {
      float4 w4 = *(const float4*)&wr[e];
      acc += er[e] * w4.x + er[e + 1] * w4.y + er[e + 2] * w4.z + er[e + 3] * w4.w;
    }
    projb[c * E_ + f] = acc;
  } else {
    // ---- Gt[set,h][e'][e] = sum_f WK[h,f,e']*WQ[h,f,e]/sqrt(E), MFMA ----
    int gb = bid - 2078;
    int h = gb & 7, set = gb >> 3;
    const float* WQ = (set ? WQi_ : WQt_) + ((size_t)h << 14);
    const float* WK = (set ? WKi_ : WKt_) + ((size_t)h << 14);
    uint* QT = sbuf;          // [e][f2 swz]
    uint* KT = sbuf + 8192;   // [e'][f2 swz]
    for (int j = t; j < 8192; j += 256) {
      int e = j & 127, f2 = j >> 7;
      int wi = (f2 << 8) + e;
      float q0 = WQ[wi], q1 = WQ[wi + 128];
      float k0 = WK[wi], k1 = WK[wi + 128];
      int idx = (e << 6) + (f2 ^ ((e & 15) << 2));
      QT[idx] = (uint)ftoh(q0) | ((uint)ftoh(q1) << 16);
      KT[idx] = (uint)ftoh(k0) | ((uint)ftoh(k1) << 16);
    }
    __syncthreads();
    int w = t >> 6, l = t & 63, lo = l & 31, hi = l >> 5;
    int m0 = w << 5;
    f32x16 acc[4];
    #pragma unroll
    for (int i = 0; i < 4; ++i)
      #pragma unroll
      for (int j = 0; j < 16; ++j) acc[i][j] = 0.0f;
    int mrow = m0 + lo;
    #pragma unroll
    for (int ks = 0; ks < 8; ++ks) {
      int f2b = (ks << 3) + (hi << 2);
      f16x8 a = *(const f16x8*)&KT[(mrow << 6) + (f2b ^ ((mrow & 15) << 2))];
      #pragma unroll
      for (int tl = 0; tl < 4; ++tl) {
        int ncol = (tl << 5) + lo;
        f16x8 b = *(const f16x8*)&QT[(ncol << 6) + (f2b ^ ((ncol & 15) << 2))];
        acc[tl] = __builtin_amdgcn_mfma_f32_32x32x16_f16(a, b, acc[tl], 0, 0, 0);
      }
    }
    const float scale = 0.08838834764831845f;   // 1/sqrt(128)
    ushort* Go = Gt + (((size_t)(set * H_ + h)) << 14);
    #pragma unroll
    for (int tl = 0; tl < 4; ++tl)
      #pragma unroll
      for (int rg = 0; rg < 16; ++rg) {
        int row = m0 + (rg & 3) + ((rg >> 2) << 3) + (hi << 2);
        int col = (tl << 5) + lo;
        Go[(row << 7) + col] = ftoh(acc[tl][rg] * scale);
      }
  }
}

// ==================== 2. fused attention (sets merged, low-barrier) ========
// grid (25, 8). No-max softmax (|S|<~2 by construction); den fused into the
// BR reduction phases; redA/redB ping-pong, ~2+L barriers per m-half.
__global__ __launch_bounds__(512) void k_attn_fused(
    const ushort* __restrict__ emb16, const ushort* __restrict__ GtAll,
    const int* __restrict__ cnt, const int* __restrict__ lst,
    const float* __restrict__ bst, const float* __restrict__ bsi,
    float* __restrict__ BRt, float* __restrict__ BRi) {
  int r = blockIdx.x, h = blockIdx.y;
  int L0 = cnt[r], L1 = cnt[R_ + r];
  if (L0 == 0 && L1 == 0) return;
  __shared__ ushort ELN[256 * 128];   // 64KB (staged once)
  __shared__ ushort TA[128 * 128];    // Gt stage, then T rows 0..127
  __shared__ ushort TB[128 * 128];    // T rows 128..255
  __shared__ float redA[8 * 128];
  __shared__ float redB[8 * 128];
  int t = threadIdx.x;
  int w = t >> 6, l = t & 63, lo = l & 31, hi = l >> 5;
  int n = (w << 5) + lo;
  int rrow = n & 127;
  int baseRow = (w << 5) + (hi << 2);

  // ---- stage ELN (swizzled) once: shared by both sets ----
  const uint4* Ep = (const uint4*)(emb16 + ((size_t)r << 15));
  for (int c = t; c < 4096; c += 512) {
    int nn = c >> 4, s = c & 15;
    uint4 v = Ep[c];
    *(uint4*)&ELN[(nn << 7) + ((s << 3) ^ ((nn & 15) << 3))] = v;
  }

  for (int set = 0; set < 2; ++set) {
    int L = set ? L1 : L0;
    if (L == 0) continue;
    int g = set * R_ + r;
    // ---- stage Gt (swizzled) into TA ----
    const uint4* Gp = (const uint4*)(GtAll + ((size_t)(set * H_ + h) << 14));
    for (int c = t; c < 2048; c += 512) {
      int e2 = c >> 4, s = c & 15;
      uint4 v = Gp[c];
      *(uint4*)&TA[(e2 << 7) + ((s << 3) ^ ((e2 & 15) << 3))] = v;
    }
    __syncthreads();
    // ---- T = ELN * Gt ----
    f32x16 tacc[4];
    #pragma unroll
    for (int i = 0; i < 4; ++i)
      #pragma unroll
      for (int j = 0; j < 16; ++j) tacc[i][j] = 0.0f;
    #pragma unroll
    for (int ks = 0; ks < 8; ++ks) {
      f16x8 a = *(const f16x8*)&ELN[(n << 7) + (((ks << 4) + (hi << 3)) ^ ((n & 15) << 3))];
      #pragma unroll
      for (int tl = 0; tl < 4; ++tl) {
        int f = (tl << 5) + lo;
        f16x8 b = *(const f16x8*)&TA[(f << 7) + (((ks << 4) + (hi << 3)) ^ ((f & 15) << 3))];
        tacc[tl] = __builtin_amdgcn_mfma_f32_32x32x16_f16(a, b, tacc[tl], 0, 0, 0);
      }
    }
    __syncthreads();   // all waves done reading Gt from TA
    {
      ushort* Tl = (w < 4) ? TA : TB;
      #pragma unroll
      for (int tl = 0; tl < 4; ++tl)
        #pragma unroll
        for (int rg = 0; rg < 16; ++rg) {
          int row = ((w & 3) << 5) + (rg & 3) + ((rg >> 2) << 3) + (hi << 2);
          int col = (tl << 5) + lo;
          Tl[(row << 7) + (col ^ ((row & 15) << 3))] = ftoh(tacc[tl][rg]);
        }
    }
    __syncthreads();
    const float* wv = set ? bsi : bst;
    float* BR = set ? BRi : BRt;
    const ushort* Tl = (w < 4) ? TA : TB;
    for (int mh = 0; mh < 2; ++mh) {
      f32x16 acc[4];
      #pragma unroll
      for (int i = 0; i < 4; ++i)
        #pragma unroll
        for (int j = 0; j < 16; ++j) acc[i][j] = 0.0f;
      #pragma unroll
      for (int ks = 0; ks < 8; ++ks) {
        f16x8 a = *(const f16x8*)&Tl[(rrow << 7) + (((ks << 4) + (hi << 3)) ^ ((rrow & 15) << 3))];
        #pragma unroll
        for (int tl = 0; tl < 4; ++tl) {
          int m = (mh << 7) + (tl << 5) + lo;
          f16x8 b = *(const f16x8*)&ELN[(m << 7) + (((ks << 4) + (hi << 3)) ^ ((m & 15) << 3))];
          acc[tl] = __builtin_amdgcn_mfma_f32_32x32x16_f16(a, b, acc[tl], 0, 0, 0);
        }
      }
      // ---- exp in place, NO max subtraction (|S| <~ 2 by construction) ----
      // per-wave den partial -> redA, num(li=0) partial -> redB
      {
        int ll = lst[g * 64 + 0];
        float wreg[16];
        #pragma unroll
        for (int rg = 0; rg < 16; ++rg)
          wreg[rg] = wv[ll * N_ + baseRow + (rg & 3) + ((rg >> 2) << 3)];
        #pragma unroll
        for (int tl = 0; tl < 4; ++tl) {
          float ds = 0.0f, ns = 0.0f;
          #pragma unroll
          for (int rg = 0; rg < 16; ++rg) {
            float e = __expf(acc[tl][rg]);
            acc[tl][rg] = e;
            ds += e;
            ns += wreg[rg] * e;
          }
          ds += __shfl_xor(ds, 32);
          ns += __shfl_xor(ns, 32);
          if (hi == 0) {
            redA[(w << 7) + (tl << 5) + lo] = ds;
            redB[(w << 7) + (tl << 5) + lo] = ns;
          }
        }
      }
      __syncthreads();
      float den_reg = 0.0f;
      if (t < 128) {
        float ds = 0.0f, ns = 0.0f;
        #pragma unroll
        for (int ww = 0; ww < 8; ++ww) {
          ds += redA[(ww << 7) + t];
          ns += redB[(ww << 7) + t];
        }
        den_reg = ds;
        int ll = lst[g * 64 + 0];
        BR[((size_t)ll * N_ + (mh << 7) + t) * H_ + h] = ns / ds;
      }
      // ---- remaining group members, two per phase ----
      for (int li = 1; li < L; li += 2) {
        __syncthreads();   // prior reads of redA/redB complete
        {
          int ll = lst[g * 64 + li];
          float wreg[16];
          #pragma unroll
          for (int rg = 0; rg < 16; ++rg)
            wreg[rg] = wv[ll * N_ + baseRow + (rg & 3) + ((rg >> 2) << 3)];
          #pragma unroll
          for (int tl = 0; tl < 4; ++tl) {
            float ns = 0.0f;
            #pragma unroll
            for (int rg = 0; rg < 16; ++rg) ns += wreg[rg] * acc[tl][rg];
            ns += __shfl_xor(ns, 32);
            if (hi == 0) redA[(w << 7) + (tl << 5) + lo] = ns;
          }
        }
        if (li + 1 < L) {
          int ll = lst[g * 64 + li + 1];
          float wreg[16];
          #pragma unroll
          for (int rg = 0; rg < 16; ++rg)
            wreg[rg] = wv[ll * N_ + baseRow + (rg & 3) + ((rg >> 2) << 3)];
          #pragma unroll
          for (int tl = 0; tl < 4; ++tl) {
            float ns = 0.0f;
            #pragma unroll
            for (int rg = 0; rg < 16; ++rg) ns += wreg[rg] * acc[tl][rg];
            ns += __shfl_xor(ns, 32);
            if (hi == 0) redB[(w << 7) + (tl << 5) + lo] = ns;
          }
        }
        __syncthreads();
        if (t < 128) {
          float ns = 0.0f;
          #pragma unroll
          for (int ww = 0; ww < 8; ++ww) ns += redA[(ww << 7) + t];
          int ll = lst[g * 64 + li];
          BR[((size_t)ll * N_ + (mh << 7) + t) * H_ + h] = ns / den_reg;
          if (li + 1 < L) {
            float n2 = 0.0f;
            #pragma unroll
            for (int ww = 0; ww < 8; ++ww) n2 += redB[(ww << 7) + t];
            int l2 = lst[g * 64 + li + 1];
            BR[((size_t)l2 * N_ + (mh << 7) + t) * H_ + h] = n2 / den_reg;
          }
        }
      }
      __syncthreads();   // end-of-mh fence (protects redA/redB and TA/TB)
    }
  }
}

// ==================== 3. BS + CS + OS, with per-block LN partials ==========
__global__ __launch_bounds__(256) void k_bscs_os(
    const float* __restrict__ BRt, const float* __restrict__ BRi,
    const float* __restrict__ Ssq, const float* __restrict__ Tsq,
    const float* __restrict__ emb, const float* __restrict__ projb,
    float* __restrict__ outBS, float* __restrict__ outCS,
    float* __restrict__ outOS,
    float2* __restrict__ pBS, float2* __restrict__ pCS,
    float2* __restrict__ pOS) {
  __shared__ float pr[8][E_];
  __shared__ float rb[4][4];
  int bid = blockIdx.x, t = threadIdx.x;
  if (bid < 1600) {
    int i = bid * 256 + t;
    int n = i & 255, c = (i >> 8) & 63, l = i >> 14;
    const float4* a = (const float4*)&BRt[((size_t)l * N_ + n) * H_];
    const float4* b = (const float4*)&BRi[((size_t)c * N_ + n) * H_];
    float4 a0 = a[0], a1 = a[1], b0 = b[0], b1 = b[1];
    float dot = a0.x * b0.x + a0.y * b0.y + a0.z * b0.z + a0.w * b0.w
              + a1.x * b1.x + a1.y * b1.y + a1.z * b1.z + a1.w * b1.w;
    float na = a0.x * a0.x + a0.y * a0.y + a0.z * a0.z + a0.w * a0.w
             + a1.x * a1.x + a1.y * a1.y + a1.z * a1.z + a1.w * a1.w;
    float nb = b0.x * b0.x + b0.y * b0.y + b0.z * b0.z + b0.w * b0.w
             + b1.x * b1.x + b1.y * b1.y + b1.z * b1.z + b1.w * b1.w;
    float bsv = dot / fmaxf(sqrtf(na) * sqrtf(nb), 1e-15f);
    outBS[i] = bsv;

    const float4* sp = (const float4*)&Ssq[((size_t)l * N_ + n) * SQS];
    const float4* tp = (const float4*)&Tsq[((size_t)c * N_ + n) * SQS];
    float d2 = 0.0f;
    #pragma unroll
    for (int j = 0; j < 7; ++j) {
      float4 sv = sp[j], tv = tp[j];
      d2 += sv.x * tv.x + sv.y * tv.y + sv.z * tv.z + sv.w * tv.w;
    }
    float csv = logf(d2) * (1.0f / 27.0f);
    outCS[i] = csv;
    float s0 = waveReduceSum(bsv), q0 = waveReduceSum(bsv * bsv);
    float s1 = waveReduceSum(csv), q1 = waveReduceSum(csv * csv);
    if ((t & 63) == 0) {
      int wv = t >> 6;
      rb[wv][0] = s0; rb[wv][1] = q0; rb[wv][2] = s1; rb[wv][3] = q1;
    }
    __syncthreads();
    if (t == 0) {
      float A = 0, B = 0, Cq = 0, D = 0;
      #pragma unroll
      for (int k = 0; k < 4; ++k) { A += rb[k][0]; B += rb[k][1]; Cq += rb[k][2]; D += rb[k][3]; }
      pBS[bid] = make_float2(A, B);
      pCS[bid] = make_float2(Cq, D);
    }
  } else {
    int o = bid - 1600;
    int l = o >> 3, cg = o & 7;
    for (int i = t; i < 1024; i += 256)
      pr[i >> 7][i & 127] = projb[(cg * 8 + (i >> 7)) * E_ + (i & 127)];
    __syncthreads();
    const float* er = &emb[((size_t)(l * N_) + t) << 7];
    float acc[8] = {0, 0, 0, 0, 0, 0, 0, 0};
    for (int e = 0; e < 128; e += 4) {
      float4 v = *(const float4*)&er[e];
      #pragma unroll
      for (int c = 0; c < 8; ++c)
        acc[c] += v.x * pr[c][e] + v.y * pr[c][e + 1] + v.z * pr[c][e + 2] + v.w * pr[c][e + 3];
    }
    float s = 0.0f, q = 0.0f;
    #pragma unroll
    for (int c = 0; c < 8; ++c) {
      outOS[((size_t)l * C_ + cg * 8 + c) * N_ + t] = acc[c];
      s += acc[c];
      q += acc[c] * acc[c];
    }
    s = waveReduceSum(s);
    q = waveReduceSum(q);
    if ((t & 63) == 0) { int wv = t >> 6; rb[wv][0] = s; rb[wv][1] = q; }
    __syncthreads();
    if (t == 0) {
      float A = 0, B = 0;
      #pragma unroll
      for (int k = 0; k < 4; ++k) { A += rb[k][0]; B += rb[k][1]; }
      pOS[o] = make_float2(A, B);
    }
  }
}

// ==================== 4. LN apply (single pass, stats from partials) =======
__global__ __launch_bounds__(256) void k_ln_apply(
    float* __restrict__ out,
    const float2* __restrict__ pBS, const float2* __restrict__ pCS,
    const float2* __restrict__ pOS,
    const float* __restrict__ w0, const float* __restrict__ b0,
    const float* __restrict__ w1, const float* __restrict__ b1,
    const float* __restrict__ w2, const float* __restrict__ b2) {
  int r = blockIdx.x, o = blockIdx.y, chunk = blockIdx.z;   // (25,3,8)
  int t = threadIdx.x;
  __shared__ float sm[2];
  if (t < 64) {
    float s = 0.0f, q = 0.0f;
    if (o == 2) {
      if (t < 8) { float2 v = pOS[r * 8 + t]; s = v.x; q = v.y; }
    } else {
      const float2* pp = (o == 0) ? pBS : pCS;
      float2 v = pp[r * 64 + t]; s = v.x; q = v.y;
    }
    #pragma unroll
    for (int off = 32; off > 0; off >>= 1) {
      s += __shfl_xor(s, off);
      q += __shfl_xor(q, off);
    }
    if (t == 0) {
      float m = s * (1.0f / 16384.0f);
      float v = q * (1.0f / 16384.0f) - m * m;
      sm[0] = m;
      sm[1] = 1.0f / sqrtf(v + 1e-5f);
    }
  }
  __syncthreads();
  float m = sm[0], inv = sm[1];
  const float* w = (o == 0) ? w0 : (o == 1) ? w1 : w2;
  const float* b = (o == 0) ? b0 : (o == 1) ? b1 : b2;
  float* x = out + (size_t)o * 409600 + (size_t)r * 16384;
  int base = chunk * 2048;
  #pragma unroll
  for (int k = 0; k < 8; ++k) {
    int pos = base + k * 256 + t;
    x[pos] = (x[pos] - m) * inv * w[pos] + b[pos];
  }
}

// ==================== host launcher ========================================
extern "C" void kernel_launch(void* const* d_in, const int* in_sizes, int n_in,
                              void* d_out, int out_size, void* d_ws, size_t ws_size,
                              hipStream_t stream) {
  const float* bus_t  = (const float*)d_in[0];
  const float* bus_i  = (const float*)d_in[1];
  const float* cus_t  = (const float*)d_in[2];
  const float* cus_i  = (const float*)d_in[3];
  const int*   idx_t  = (const int*)d_in[4];
  const int*   idx_i  = (const int*)d_in[5];
  const int*   cov    = (const int*)d_in[6];
  const float* emb    = (const float*)d_in[7];
  const float* ln_w   = (const float*)d_in[8];
  const float* ln_b   = (const float*)d_in[9];
  const float* WQ_trg = (const float*)d_in[10];
  const float* WK_trg = (const float*)d_in[11];
  const float* WQ_inf = (const float*)d_in[12];
  const float* WK_inf = (const float*)d_in[13];
  const float* W_os   = (const float*)d_in[14];
  const float* b_os   = (const float*)d_in[15];
  const float* bs_w   = (const float*)d_in[16];
  const float* bs_b   = (const float*)d_in[17];
  const float* cs_w   = (const float*)d_in[18];
  const float* cs_b   = (const float*)d_in[19];
  const float* os_w   = (const float*)d_in[20];
  const float* os_b   = (const float*)d_in[21];

  float* ws = (float*)d_ws;
  ushort* emb16 = (ushort*)ws;                 // 409600 f32 slots
  float* p = ws + 409600;
  ushort* Gt = (ushort*)p;   p += 131072;      // 16 x 128 x 128 f16
  float* bst = p;            p += 6400;
  float* bsi = p;            p += 16384;
  float* Ssq = p;            p += R_ * N_ * SQS;   // 179200
  float* Tsq = p;            p += C_ * N_ * SQS;   // 458752
  float* BRt = p;            p += 51200;
  float* BRi = p;            p += 131072;
  float* projb = p;          p += 8192;
  int* cnt = (int*)p;        p += 64;
  int* lst = (int*)p;        p += 3200;
  float2* pBS = (float2*)p;  p += 3200;
  float2* pCS = (float2*)p;  p += 3200;
  float2* pOS = (float2*)p;  p += 400;

  float* outBS = (float*)d_out;
  float* outCS = outBS + 409600;
  float* outOS = outCS + 409600;

  k_prep<<<2094, 256, 0, stream>>>(emb, ln_w, ln_b, emb16,
                                   bus_t, bus_i, bst, bsi,
                                   cus_t, cus_i, Ssq, Tsq,
                                   idx_t, idx_i, cnt, lst,
                                   cov, W_os, b_os, projb,
                                   WQ_trg, WK_trg, WQ_inf, WK_inf, Gt);
  k_attn_fused<<<dim3(R_, H_), 512, 0, stream>>>(emb16, Gt, cnt, lst,
                                                 bst, bsi, BRt, BRi);
  k_bscs_os<<<1800, 256, 0, stream>>>(BRt, BRi, Ssq, Tsq, emb, projb,
                                      outBS, outCS, outOS, pBS, pCS, pOS);
  k_ln_apply<<<dim3(R_, 3, 8), 256, 0, stream>>>(outBS, pBS, pCS, pOS,
                                                 bs_w, bs_b, cs_w, cs_b, os_w, os_b);
}